// Round 6
// baseline (43.101 us; speedup 1.0000x reference)
//
#include <hip/hip_runtime.h>

#define N  2048
#define K  8
#define NK 1024
#define TAU_C 0.5f
#define TAU_S 0.5f

// posT[x*K + k] = position of node x in client k's sorted index list, or -1.
// One thread per (x,k) cell; binary search => every cell written exactly once,
// no memset / init pass needed (graph contains only kernel nodes).
__global__ void fia_build_pos(const int* __restrict__ idx, int* __restrict__ posT) {
    int t = blockIdx.x * blockDim.x + threadIdx.x;   // t = x*K + k
    if (t < N * K) {
        int x = t >> 3;         // t / K
        int k = t & 7;          // t % K
        const int* a = idx + k * NK;                 // sorted, 1024 ints (L2-hot)
        int lo = 0, hi = NK;                         // search [lo, hi)
        #pragma unroll 1
        while (lo < hi) {
            int mid = (lo + hi) >> 1;
            if (a[mid] < x) lo = mid + 1; else hi = mid;
        }
        int p = (lo < NK && a[lo] == x) ? lo : -1;
        posT[t] = p;                                 // fully coalesced write
    }
}

__global__ void __launch_bounds__(256, 4)      // allow up to 128 VGPR: room for MLP
fia_main(const float* __restrict__ adj,
         const int* __restrict__ posT,
         float* __restrict__ out) {
    const int x  = blockIdx.y;                                   // row (block-uniform)
    const int t  = blockIdx.x * blockDim.x + threadIdx.x;
    const int y0 = t * 4;                                        // 4 consecutive columns

    // Row positions: lane-varying vector load + readlane -> uniform SGPRs
    // (guaranteed global_load; dodges the R2 graph-replay s_load staleness).
    int myix = posT[(size_t)x * K + (threadIdx.x & 7)];
    int ix[K];
    #pragma unroll
    for (int k = 0; k < K; ++k) ix[k] = __builtin_amdgcn_readlane(myix, k);

    // Column positions: 4 y * 8 k = 32 contiguous ints = 8x int4 (per-lane).
    int jv[4 * K];
    {
        const int4* pp = (const int4*)(posT + (size_t)y0 * K);
        #pragma unroll
        for (int q = 0; q < 8; ++q) {
            int4 v = pp[q];
            jv[4 * q + 0] = v.x; jv[4 * q + 1] = v.y;
            jv[4 * q + 2] = v.z; jv[4 * q + 3] = v.w;
        }
    }

    // Raw gathered values (garbage where absent -> masked in the stats pass).
    float vraw[4][K];
    #pragma unroll
    for (int yy = 0; yy < 4; ++yy)
        #pragma unroll
        for (int k = 0; k < K; ++k) vraw[yy][k] = 0.f;

    int mb[4] = {0, 0, 0, 0};

    // LOAD PHASE: issue ALL present-k gathers with no consumers of loaded data.
    #pragma unroll
    for (int k = 0; k < K; ++k) {
        if (ix[k] >= 0) {                                        // scalar branch
            const float* __restrict__ bk =
                adj + ((size_t)k * NK + (size_t)ix[k]) * NK;
            #pragma unroll
            for (int yy = 0; yy < 4; ++yy) {
                int j  = jv[yy * K + k];
                int jc = j & ~(j >> 31);                          // max(j, 0)
                vraw[yy][k] = bk[jc];                             // unconditional load
                mb[yy] |= (j >= 0) ? (1 << k) : 0;
            }
        }
    }
    // Hard scheduling fence: nothing moves across. All gathers above are ISSUED
    // before any stats consume them -> one vmcnt drain instead of ~20 serialized
    // waits (R3/R4's VGPR=28 showed the compiler re-fused load+consume to save
    // registers; this forces the 32 destinations live -> real MLP).
    __builtin_amdgcn_sched_barrier(0);

    // STATS PHASE: exact f32 rounding sequence of the reference (R1/R4-proven).
    float res[4];
    #pragma unroll
    for (int yy = 0; yy < 4; ++yy) {
        const int m = mb[yy];
        float sum = 0.f;
        #pragma unroll
        for (int k = 0; k < K; ++k) {
            bool p = (m >> k) & 1;
            sum += p ? vraw[yy][k] : 0.f;                         // masked, k-ascending
        }
        float cnt  = (float)__popc(m);
        float n    = fmaxf(cnt, 1e-5f);
        float mean = sum / n;                                     // IEEE divide

        float cs = 0.f, vs = 0.f;
        #pragma unroll
        for (int k = 0; k < K; ++k) {
            bool  p = (m >> k) & 1;
            float a = p ? vraw[yy][k] : 0.f;
            cs += (p && (a > TAU_C)) ? 1.f : 0.f;
            float d = a - mean;
            vs += p ? d * d : 0.f;                                // select blocks fma-fuse
        }
        float C = cs / n;
        float V = vs / n;
        float S = C * expf(-V);                                   // precise expf
        float r = (S > TAU_S) ? mean : 0.f;
        res[yy] = (cnt > 0.f) ? r : 0.f;
    }

    float4 o;
    o.x = res[0]; o.y = res[1]; o.z = res[2]; o.w = res[3];
    *(float4*)(out + (size_t)x * N + y0) = o;
}

extern "C" void kernel_launch(void* const* d_in, const int* in_sizes, int n_in,
                              void* d_out, int out_size, void* d_ws, size_t ws_size,
                              hipStream_t stream) {
    const float* adj  = (const float*)d_in[0];   // (K, NK, NK) f32
    const int*   idx  = (const int*)d_in[1];     // (K, NK) i32
    float*       out  = (float*)d_out;           // (N, N) f32
    int*         posT = (int*)d_ws;              // N*K ints = 64 KB

    {
        int total = N * K;                       // 16384
        int block = 256;
        int grid  = (total + block - 1) / block;
        fia_build_pos<<<grid, block, 0, stream>>>(idx, posT);
    }
    {
        dim3 block(256, 1, 1);
        dim3 grid(N / (256 * 4), N, 1);          // 2 x 2048 blocks
        fia_main<<<grid, block, 0, stream>>>(adj, posT, out);
    }
}